// Round 6
// baseline (1854.905 us; speedup 1.0000x reference)
//
#include <hip/hip_runtime.h>
#include <hip/hip_cooperative_groups.h>
#include <math.h>

// TimestepNorm forward, prefix-sum reformulation:
//   c_t   = C0 + #valid<=t
//   M_t   = C0*pm + sum(valid*x)             -> mean = M/c
//   var_t = (V2 + sum(valid*x^2) - M_t^2/c_t)/c_t,  V2 = C0*(exp(plv)+pm^2)
//
// v7: cooperative single-kernel fusion of the 3-pass scheme. v6 A/B showed
// kernel time ~103us vs ~60-65us ideal; the slack is 2 launch gaps + 2 full
// kernel-boundary vmcnt(0) drains + ramp. One kernel, grid (512,8)x128 =
// 8192 waves = exact co-residency (16 blk/CU, <=64 VGPR via
// __launch_bounds__(128,8), 0 LDS), grid.sync() between phases:
//   A: per-chunk partials (pass1)   B: wave-parallel exclusive scan (pass2)
//   C: replay + normalize epilogue, nt y-stores (pass3)
// Launcher checks hipLaunchCooperativeKernel's return and falls back to the
// verified v6 3-pass (277us) on any error.

#define T_DIM 8192
#define B_DIM 8
#define D_DIM 512
#define BD    (B_DIM * D_DIM)   // 4096 floats per time row
#define BD4   (BD / 4)          // 1024 float4 per time row
#define D4    (D_DIM / 4)       // 128 float4 per (t,b)
#define C0    2.0f              // PRIOR_COUNT
#define EPS   1e-5f

#define NCF   512               // chunks (fused + fallback primary)
#define CTF   (T_DIM / NCF)     // 16 steps per chunk
#define NWF   (CTF / 8)         // mask u64 words per chunk

namespace cg = cooperative_groups;

typedef float nt_f4 __attribute__((ext_vector_type(4)));

__device__ __forceinline__ float4 f4add(float4 a, float4 b) {
  return make_float4(a.x + b.x, a.y + b.y, a.z + b.z, a.w + b.w);
}
__device__ __forceinline__ float4 f4sub(float4 a, float4 b) {
  return make_float4(a.x - b.x, a.y - b.y, a.z - b.z, a.w - b.w);
}
__device__ __forceinline__ void ntstore4(float4 v, float4* p) {
  nt_f4 t = {v.x, v.y, v.z, v.w};
  __builtin_nontemporal_store(t, (nt_f4*)p);
}

// ======================= v7 cooperative fused kernel =======================
__global__ __launch_bounds__(128, 8) void ts_coop(
    const float* __restrict__ x, const unsigned char* __restrict__ mask,
    const float* __restrict__ pm, const float* __restrict__ plv,
    const float* __restrict__ w, const float* __restrict__ bias,
    float* __restrict__ s1p, float* __restrict__ s2p, float* __restrict__ cnt,
    float* __restrict__ out) {
  const int chunk = blockIdx.x;           // 0..NCF-1
  const int b     = blockIdx.y;           // 0..B-1
  const int tid   = threadIdx.x;          // 0..127
  const int t0    = chunk * CTF;
  const int col   = b * D4 + tid;
  const float4* xp = (const float4*)x;

  // mask words: loaded once, reused in phases A and C
  unsigned long long mw[NWF];
  const unsigned long long* m8 =
      (const unsigned long long*)(mask + b * T_DIM + t0);
#pragma unroll
  for (int j = 0; j < NWF; ++j) mw[j] = m8[j];

  // ---------------- phase A: per-chunk partial sums ----------------
  {
    float4 s1 = make_float4(0.f, 0.f, 0.f, 0.f);
    float4 s2 = make_float4(0.f, 0.f, 0.f, 0.f);
    float c = 0.f;
#pragma unroll
    for (int i = 0; i < CTF; ++i) {
      float valid = ((mw[i >> 3] >> ((i & 7) * 8)) & 0xffULL) ? 0.f : 1.f;
      float4 v = xp[(t0 + i) * BD4 + col];
      c += valid;
      s1.x += valid * v.x; s2.x += valid * v.x * v.x;
      s1.y += valid * v.y; s2.y += valid * v.y * v.y;
      s1.z += valid * v.z; s2.z += valid * v.z * v.z;
      s1.w += valid * v.w; s2.w += valid * v.w * v.w;
    }
    const int pidx = chunk * BD4 + col;
    ((float4*)s1p)[pidx] = s1;
    ((float4*)s2p)[pidx] = s2;
    if (tid == 0) cnt[chunk * B_DIM + b] = c;
  }

  __threadfence();
  cg::this_grid().sync();

  // ---------------- phase B: wave-parallel exclusive scan ----------------
  // 2*BD4 float4-columns + B_DIM scalar columns; one wave per column.
  {
    constexpr int KPL = NCF / 64;  // 8 chunks per lane
    const int lin  = blockIdx.y * gridDim.x + blockIdx.x;  // 0..4095
    const int wid  = lin * 2 + (tid >> 6);                 // 2 waves/block
    const int lane = tid & 63;

    if (wid < 2 * BD4) {
      float4* base = (float4*)(wid < BD4 ? s1p : s2p);
      const int scol = wid & (BD4 - 1);
      float4 vals[KPL];
#pragma unroll
      for (int j = 0; j < KPL; ++j)
        vals[j] = ((float4*)base)[(lane * KPL + j) * BD4 + scol];
#pragma unroll
      for (int j = 1; j < KPL; ++j) vals[j] = f4add(vals[j], vals[j - 1]);
      float4 tot = vals[KPL - 1];
      float4 inc = tot;
#pragma unroll
      for (int off = 1; off < 64; off <<= 1) {
        float4 o;
        o.x = __shfl_up(inc.x, off);
        o.y = __shfl_up(inc.y, off);
        o.z = __shfl_up(inc.z, off);
        o.w = __shfl_up(inc.w, off);
        if (lane >= off) inc = f4add(inc, o);
      }
      float4 excl = f4sub(inc, tot);
#pragma unroll
      for (int j = KPL - 1; j >= 1; --j)
        base[(lane * KPL + j) * BD4 + scol] = f4add(excl, vals[j - 1]);
      base[(lane * KPL) * BD4 + scol] = excl;
    } else if (wid < 2 * BD4 + B_DIM) {
      const int sb = wid - 2 * BD4;
      float vals[KPL];
#pragma unroll
      for (int j = 0; j < KPL; ++j)
        vals[j] = cnt[(lane * KPL + j) * B_DIM + sb];
#pragma unroll
      for (int j = 1; j < KPL; ++j) vals[j] += vals[j - 1];
      float tot = vals[KPL - 1];
      float inc = tot;
#pragma unroll
      for (int off = 1; off < 64; off <<= 1) {
        float o = __shfl_up(inc, off);
        if (lane >= off) inc += o;
      }
      float excl = inc - tot;
#pragma unroll
      for (int j = KPL - 1; j >= 1; --j)
        cnt[(lane * KPL + j) * B_DIM + sb] = excl + vals[j - 1];
      cnt[lane * KPL * B_DIM + sb] = excl;
    }
  }

  __threadfence();
  cg::this_grid().sync();

  // ---------------- phase C: replay + normalize epilogue ----------------
  {
    float4 S1 = ((const float4*)s1p)[chunk * BD4 + col];
    float4 S2 = ((const float4*)s2p)[chunk * BD4 + col];
    float c = C0 + cnt[chunk * B_DIM + b];

    float4 pm4 = ((const float4*)pm)[tid];
    float4 lv4 = ((const float4*)plv)[tid];
    float4 g4  = ((const float4*)w)[tid];
    float4 be4 = ((const float4*)bias)[tid];
    g4.x += 1.f; g4.y += 1.f; g4.z += 1.f; g4.w += 1.f;
    float M0x = C0 * pm4.x, M0y = C0 * pm4.y, M0z = C0 * pm4.z,
          M0w = C0 * pm4.w;
    float V2x = C0 * (__expf(lv4.x) + pm4.x * pm4.x);
    float V2y = C0 * (__expf(lv4.y) + pm4.y * pm4.y);
    float V2z = C0 * (__expf(lv4.z) + pm4.z * pm4.z);
    float V2w = C0 * (__expf(lv4.w) + pm4.w * pm4.w);

    float4* op = (float4*)out;
#pragma unroll
    for (int i = 0; i < CTF; ++i) {
      float valid = ((mw[i >> 3] >> ((i & 7) * 8)) & 0xffULL) ? 0.f : 1.f;
      const int xi = (t0 + i) * BD4 + col;
      float4 v = xp[xi];  // L3-resident (phase A streamed it)
      c += valid;
      float rc = __builtin_amdgcn_rcpf(c);
      float4 y;
      {
        S1.x += valid * v.x; S2.x += valid * v.x * v.x;
        float M = M0x + S1.x;
        float mean = M * rc;
        float var = (V2x + S2.x - M * M * rc) * rc;
        y.x = (v.x - mean) * __builtin_amdgcn_rsqf(var + EPS) * g4.x + be4.x;
      }
      {
        S1.y += valid * v.y; S2.y += valid * v.y * v.y;
        float M = M0y + S1.y;
        float mean = M * rc;
        float var = (V2y + S2.y - M * M * rc) * rc;
        y.y = (v.y - mean) * __builtin_amdgcn_rsqf(var + EPS) * g4.y + be4.y;
      }
      {
        S1.z += valid * v.z; S2.z += valid * v.z * v.z;
        float M = M0z + S1.z;
        float mean = M * rc;
        float var = (V2z + S2.z - M * M * rc) * rc;
        y.z = (v.z - mean) * __builtin_amdgcn_rsqf(var + EPS) * g4.z + be4.z;
      }
      {
        S1.w += valid * v.w; S2.w += valid * v.w * v.w;
        float M = M0w + S1.w;
        float mean = M * rc;
        float var = (V2w + S2.w - M * M * rc) * rc;
        y.w = (v.w - mean) * __builtin_amdgcn_rsqf(var + EPS) * g4.w + be4.w;
      }
      ntstore4(y, &op[xi]);  // y never re-read: no write-allocate
    }
  }
}

// ======================= v6 3-pass fallback =======================
template <int NC>
__global__ __launch_bounds__(128) void ts_pass1(
    const float* __restrict__ x, const unsigned char* __restrict__ mask,
    float* __restrict__ s1p, float* __restrict__ s2p, float* __restrict__ cnt) {
  constexpr int CT = T_DIM / NC;
  constexpr int NW = CT / 8;
  const int chunk = blockIdx.x;
  const int b     = blockIdx.y;
  const int tid   = threadIdx.x;
  const int t0    = chunk * CT;
  const float4* xp = (const float4*)x;

  unsigned long long mw[NW];
  const unsigned long long* m8 =
      (const unsigned long long*)(mask + b * T_DIM + t0);
#pragma unroll
  for (int j = 0; j < NW; ++j) mw[j] = m8[j];

  float4 s1 = make_float4(0.f, 0.f, 0.f, 0.f);
  float4 s2 = make_float4(0.f, 0.f, 0.f, 0.f);
  float c = 0.f;
#pragma unroll 8
  for (int i = 0; i < CT; ++i) {
    float valid = ((mw[i >> 3] >> ((i & 7) * 8)) & 0xffULL) ? 0.f : 1.f;
    float4 v = xp[(t0 + i) * BD4 + b * D4 + tid];
    c += valid;
    s1.x += valid * v.x; s2.x += valid * v.x * v.x;
    s1.y += valid * v.y; s2.y += valid * v.y * v.y;
    s1.z += valid * v.z; s2.z += valid * v.z * v.z;
    s1.w += valid * v.w; s2.w += valid * v.w * v.w;
  }
  const int pidx = chunk * BD4 + b * D4 + tid;
  ((float4*)s1p)[pidx] = s1;
  ((float4*)s2p)[pidx] = s2;
  if (tid == 0) cnt[chunk * B_DIM + b] = c;
}

template <int NC>
__global__ __launch_bounds__(256) void ts_pass2(
    float* __restrict__ s1p, float* __restrict__ s2p, float* __restrict__ cnt) {
  constexpr int KPL = NC / 64;
  const int wid  = (blockIdx.x * 256 + threadIdx.x) >> 6;
  const int lane = threadIdx.x & 63;

  if (wid < 2 * BD4) {
    float4* base = (float4*)(wid < BD4 ? s1p : s2p);
    const int col = wid & (BD4 - 1);
    float4 vals[KPL];
#pragma unroll
    for (int j = 0; j < KPL; ++j)
      vals[j] = base[(lane * KPL + j) * BD4 + col];
#pragma unroll
    for (int j = 1; j < KPL; ++j) vals[j] = f4add(vals[j], vals[j - 1]);
    float4 tot = vals[KPL - 1];
    float4 inc = tot;
#pragma unroll
    for (int off = 1; off < 64; off <<= 1) {
      float4 o;
      o.x = __shfl_up(inc.x, off);
      o.y = __shfl_up(inc.y, off);
      o.z = __shfl_up(inc.z, off);
      o.w = __shfl_up(inc.w, off);
      if (lane >= off) inc = f4add(inc, o);
    }
    float4 excl = f4sub(inc, tot);
#pragma unroll
    for (int j = KPL - 1; j >= 1; --j)
      base[(lane * KPL + j) * BD4 + col] = f4add(excl, vals[j - 1]);
    base[(lane * KPL) * BD4 + col] = excl;
  } else if (wid < 2 * BD4 + B_DIM) {
    const int b = wid - 2 * BD4;
    float vals[KPL];
#pragma unroll
    for (int j = 0; j < KPL; ++j) vals[j] = cnt[(lane * KPL + j) * B_DIM + b];
#pragma unroll
    for (int j = 1; j < KPL; ++j) vals[j] += vals[j - 1];
    float tot = vals[KPL - 1];
    float inc = tot;
#pragma unroll
    for (int off = 1; off < 64; off <<= 1) {
      float o = __shfl_up(inc, off);
      if (lane >= off) inc += o;
    }
    float excl = inc - tot;
#pragma unroll
    for (int j = KPL - 1; j >= 1; --j)
      cnt[(lane * KPL + j) * B_DIM + b] = excl + vals[j - 1];
    cnt[lane * KPL * B_DIM + b] = excl;
  }
}

template <int NC>
__global__ __launch_bounds__(128) void ts_pass3(
    const float* __restrict__ x, const unsigned char* __restrict__ mask,
    const float* __restrict__ pm, const float* __restrict__ plv,
    const float* __restrict__ w, const float* __restrict__ bias,
    const float* __restrict__ e1, const float* __restrict__ e2,
    const float* __restrict__ ecnt, float* __restrict__ out) {
  constexpr int CT = T_DIM / NC;
  constexpr int NW = CT / 8;
  const int chunk = blockIdx.x;
  const int b     = blockIdx.y;
  const int tid   = threadIdx.x;
  const int t0    = chunk * CT;
  const int col   = b * D4 + tid;

  float4 S1 = ((const float4*)e1)[chunk * BD4 + col];
  float4 S2 = ((const float4*)e2)[chunk * BD4 + col];
  float c = C0 + ecnt[chunk * B_DIM + b];

  float4 pm4 = ((const float4*)pm)[tid];
  float4 lv4 = ((const float4*)plv)[tid];
  float4 g4  = ((const float4*)w)[tid];
  float4 be4 = ((const float4*)bias)[tid];
  g4.x += 1.f; g4.y += 1.f; g4.z += 1.f; g4.w += 1.f;
  float M0x = C0 * pm4.x, M0y = C0 * pm4.y, M0z = C0 * pm4.z, M0w = C0 * pm4.w;
  float V2x = C0 * (__expf(lv4.x) + pm4.x * pm4.x);
  float V2y = C0 * (__expf(lv4.y) + pm4.y * pm4.y);
  float V2z = C0 * (__expf(lv4.z) + pm4.z * pm4.z);
  float V2w = C0 * (__expf(lv4.w) + pm4.w * pm4.w);

  unsigned long long mw[NW];
  const unsigned long long* m8 =
      (const unsigned long long*)(mask + b * T_DIM + t0);
#pragma unroll
  for (int j = 0; j < NW; ++j) mw[j] = m8[j];

  const float4* xp = (const float4*)x;
  float4* op = (float4*)out;

#pragma unroll 4
  for (int i = 0; i < CT; ++i) {
    float valid = ((mw[i >> 3] >> ((i & 7) * 8)) & 0xffULL) ? 0.f : 1.f;
    const int xi = (t0 + i) * BD4 + col;
    float4 v = xp[xi];
    c += valid;
    float rc = __builtin_amdgcn_rcpf(c);
    float4 y;
    {
      S1.x += valid * v.x; S2.x += valid * v.x * v.x;
      float M = M0x + S1.x;
      float mean = M * rc;
      float var = (V2x + S2.x - M * M * rc) * rc;
      y.x = (v.x - mean) * __builtin_amdgcn_rsqf(var + EPS) * g4.x + be4.x;
    }
    {
      S1.y += valid * v.y; S2.y += valid * v.y * v.y;
      float M = M0y + S1.y;
      float mean = M * rc;
      float var = (V2y + S2.y - M * M * rc) * rc;
      y.y = (v.y - mean) * __builtin_amdgcn_rsqf(var + EPS) * g4.y + be4.y;
    }
    {
      S1.z += valid * v.z; S2.z += valid * v.z * v.z;
      float M = M0z + S1.z;
      float mean = M * rc;
      float var = (V2z + S2.z - M * M * rc) * rc;
      y.z = (v.z - mean) * __builtin_amdgcn_rsqf(var + EPS) * g4.z + be4.z;
    }
    {
      S1.w += valid * v.w; S2.w += valid * v.w * v.w;
      float M = M0w + S1.w;
      float mean = M * rc;
      float var = (V2w + S2.w - M * M * rc) * rc;
      y.w = (v.w - mean) * __builtin_amdgcn_rsqf(var + EPS) * g4.w + be4.w;
    }
    ntstore4(y, &op[xi]);
  }
}

template <int NC>
static void run_3pass(const float* x, const unsigned char* mask,
                      const float* pm, const float* plv, const float* w,
                      const float* bias, float* out, float* ws,
                      hipStream_t stream) {
  float* s1p = ws;
  float* s2p = s1p + (size_t)NC * BD;
  float* cnt = s2p + (size_t)NC * BD;
  dim3 grid(NC, B_DIM);
  ts_pass1<NC><<<grid, 128, 0, stream>>>(x, mask, s1p, s2p, cnt);
  const int scan_waves = 2 * BD4 + B_DIM;
  const int scan_blocks = (scan_waves + 3) / 4;
  ts_pass2<NC><<<scan_blocks, 256, 0, stream>>>(s1p, s2p, cnt);
  ts_pass3<NC><<<grid, 128, 0, stream>>>(x, mask, pm, plv, w, bias, s1p, s2p,
                                         cnt, out);
}

// ---------------- launch ----------------
extern "C" void kernel_launch(void* const* d_in, const int* in_sizes, int n_in,
                              void* d_out, int out_size, void* d_ws,
                              size_t ws_size, hipStream_t stream) {
  const float* x    = (const float*)d_in[0];
  const float* pm   = (const float*)d_in[1];
  const float* plv  = (const float*)d_in[2];
  const float* w    = (const float*)d_in[3];
  const float* bias = (const float*)d_in[4];
  const unsigned char* mask = (const unsigned char*)d_in[5];
  float* out = (float*)d_out;
  float* ws  = (float*)d_ws;

  const size_t need512 = ((size_t)2 * 512 * BD + 512 * B_DIM) * sizeof(float);
  const size_t need256 = ((size_t)2 * 256 * BD + 256 * B_DIM) * sizeof(float);

  if (ws_size >= need512) {
    float* s1p = ws;
    float* s2p = s1p + (size_t)NCF * BD;
    float* cnt = s2p + (size_t)NCF * BD;
    void* args[] = {(void*)&x,   (void*)&mask, (void*)&pm,  (void*)&plv,
                    (void*)&w,   (void*)&bias, (void*)&s1p, (void*)&s2p,
                    (void*)&cnt, (void*)&out};
    hipError_t e = hipLaunchCooperativeKernel(
        reinterpret_cast<const void*>(&ts_coop), dim3(NCF, B_DIM), dim3(128),
        args, 0, stream);
    if (e == hipSuccess) return;
    // cooperative launch unavailable -> verified 3-pass fallback
    run_3pass<512>(x, mask, pm, plv, w, bias, out, ws, stream);
  } else if (ws_size >= need256) {
    run_3pass<256>(x, mask, pm, plv, w, bias, out, ws, stream);
  } else {
    run_3pass<128>(x, mask, pm, plv, w, bias, out, ws, stream);
  }
}

// Round 7
// 287.159 us; speedup vs baseline: 6.4595x; 6.4595x over previous
//
#include <hip/hip_runtime.h>
#include <math.h>

// TimestepNorm forward, prefix-sum reformulation:
//   c_t   = C0 + #valid<=t
//   M_t   = C0*pm + sum(valid*x)             -> mean = M/c
//   var_t = (V2 + sum(valid*x^2) - M_t^2/c_t)/c_t,  V2 = C0*(exp(plv)+pm^2)
//
// v8 = v6 (verified 277us) with the pass2/pass3 coupling slimmed:
//   - pass2 no longer scans in-place (34 MB write-back); it reads chunk
//     partials and writes only SUPERCHUNK (G=16) exclusive prefixes
//     (4.2 MB). Wave-parallel as before: one wave per column.
//   - pass3 prologue: prefix = sup_excl[chunk/16] + sum of <=15 neighbor
//     chunk partials (L3-resident). Main loop unchanged; nt y-stores kept.
// Dead ends so far (kept out): decoupled lookback (v3, 914us: serial chain
// latency), cooperative grid.sync fusion (v7, 1725us: multi-XCD software
// barrier cost), nt x-loads (v5/v6 A/B: neutral).
// Fixed harness cost ~174us (poison fills) is untouchable from kernel code.

#define T_DIM 8192
#define B_DIM 8
#define D_DIM 512
#define BD    (B_DIM * D_DIM)   // 4096 floats per time row
#define BD4   (BD / 4)          // 1024 float4 per time row
#define D4    (D_DIM / 4)       // 128 float4 per (t,b)
#define C0    2.0f              // PRIOR_COUNT
#define EPS   1e-5f

#define NCF   512               // chunks
#define CTF   (T_DIM / NCF)     // 16 steps per chunk
#define NWF   (CTF / 8)         // mask u64 words per chunk
#define G     16                // chunks per superchunk
#define NSC   (NCF / G)         // 32 superchunks

typedef float nt_f4 __attribute__((ext_vector_type(4)));

__device__ __forceinline__ float4 f4add(float4 a, float4 b) {
  return make_float4(a.x + b.x, a.y + b.y, a.z + b.z, a.w + b.w);
}
__device__ __forceinline__ float4 f4sub(float4 a, float4 b) {
  return make_float4(a.x - b.x, a.y - b.y, a.z - b.z, a.w - b.w);
}
__device__ __forceinline__ void ntstore4(float4 v, float4* p) {
  nt_f4 t = {v.x, v.y, v.z, v.w};
  __builtin_nontemporal_store(t, (nt_f4*)p);
}

// ---------------- pass1: per-chunk partial sums ----------------
__global__ __launch_bounds__(128) void ts_pass1(
    const float* __restrict__ x, const unsigned char* __restrict__ mask,
    float* __restrict__ s1p, float* __restrict__ s2p, float* __restrict__ cnt) {
  const int chunk = blockIdx.x;
  const int b     = blockIdx.y;
  const int tid   = threadIdx.x;
  const int t0    = chunk * CTF;
  const float4* xp = (const float4*)x;

  unsigned long long mw[NWF];
  const unsigned long long* m8 =
      (const unsigned long long*)(mask + b * T_DIM + t0);
#pragma unroll
  for (int j = 0; j < NWF; ++j) mw[j] = m8[j];

  float4 s1 = make_float4(0.f, 0.f, 0.f, 0.f);
  float4 s2 = make_float4(0.f, 0.f, 0.f, 0.f);
  float c = 0.f;
#pragma unroll
  for (int i = 0; i < CTF; ++i) {
    float valid = ((mw[i >> 3] >> ((i & 7) * 8)) & 0xffULL) ? 0.f : 1.f;
    float4 v = xp[(t0 + i) * BD4 + b * D4 + tid];
    c += valid;
    s1.x += valid * v.x; s2.x += valid * v.x * v.x;
    s1.y += valid * v.y; s2.y += valid * v.y * v.y;
    s1.z += valid * v.z; s2.z += valid * v.z * v.z;
    s1.w += valid * v.w; s2.w += valid * v.w * v.w;
  }
  const int pidx = chunk * BD4 + b * D4 + tid;
  ((float4*)s1p)[pidx] = s1;
  ((float4*)s2p)[pidx] = s2;
  if (tid == 0) cnt[chunk * B_DIM + b] = c;
}

// -------- pass2: superchunk exclusive prefixes (read-mostly) --------
// One wave per column. Lane l sums chunks [8l, 8l+8); inclusive wave scan of
// lane totals; superchunk s (chunks [16s,16s+16)) exclusive prefix = scan
// value at lane 2s-1, fetched by lane 2s via shfl_up(1). Writes only
// NSC=32 values per column (4.2 MB total vs v6's 34 MB in-place scan).
__global__ __launch_bounds__(256) void ts_pass2sup(
    const float* __restrict__ s1p, const float* __restrict__ s2p,
    const float* __restrict__ cnt, float* __restrict__ sup1,
    float* __restrict__ sup2, float* __restrict__ supc) {
  constexpr int KPL = NCF / 64;  // 8 chunks per lane
  const int wid  = (blockIdx.x * 256 + threadIdx.x) >> 6;
  const int lane = threadIdx.x & 63;

  if (wid < 2 * BD4) {
    const float4* base = (const float4*)(wid < BD4 ? s1p : s2p);
    float4* supo = (float4*)(wid < BD4 ? sup1 : sup2);
    const int col = wid & (BD4 - 1);
    float4 tot = make_float4(0.f, 0.f, 0.f, 0.f);
#pragma unroll
    for (int j = 0; j < KPL; ++j)
      tot = f4add(tot, base[(lane * KPL + j) * BD4 + col]);
    float4 inc = tot;
#pragma unroll
    for (int off = 1; off < 64; off <<= 1) {
      float4 o;
      o.x = __shfl_up(inc.x, off);
      o.y = __shfl_up(inc.y, off);
      o.z = __shfl_up(inc.z, off);
      o.w = __shfl_up(inc.w, off);
      if (lane >= off) inc = f4add(inc, o);
    }
    float4 prev;
    prev.x = __shfl_up(inc.x, 1);
    prev.y = __shfl_up(inc.y, 1);
    prev.z = __shfl_up(inc.z, 1);
    prev.w = __shfl_up(inc.w, 1);
    if ((lane & 1) == 0) {
      float4 e = (lane == 0) ? make_float4(0.f, 0.f, 0.f, 0.f) : prev;
      supo[(lane >> 1) * BD4 + col] = e;
    }
  } else if (wid < 2 * BD4 + B_DIM) {
    const int b = wid - 2 * BD4;
    float tot = 0.f;
#pragma unroll
    for (int j = 0; j < KPL; ++j) tot += cnt[(lane * KPL + j) * B_DIM + b];
    float inc = tot;
#pragma unroll
    for (int off = 1; off < 64; off <<= 1) {
      float o = __shfl_up(inc, off);
      if (lane >= off) inc += o;
    }
    float prev = __shfl_up(inc, 1);
    if ((lane & 1) == 0)
      supc[(lane >> 1) * B_DIM + b] = (lane == 0) ? 0.f : prev;
  }
}

// ---------------- pass3: hierarchical prologue + replay ----------------
__global__ __launch_bounds__(128) void ts_pass3(
    const float* __restrict__ x, const unsigned char* __restrict__ mask,
    const float* __restrict__ pm, const float* __restrict__ plv,
    const float* __restrict__ w, const float* __restrict__ bias,
    const float* __restrict__ s1p, const float* __restrict__ s2p,
    const float* __restrict__ cnt, const float* __restrict__ sup1,
    const float* __restrict__ sup2, const float* __restrict__ supc,
    float* __restrict__ out) {
  const int chunk = blockIdx.x;
  const int b     = blockIdx.y;
  const int tid   = threadIdx.x;
  const int t0    = chunk * CTF;
  const int col   = b * D4 + tid;
  const int sc    = chunk >> 4;  // superchunk

  // Exclusive prefix = superchunk prefix + <=15 neighbor chunk partials
  // (all L3-resident; independent loads, pipelined).
  float4 S1 = ((const float4*)sup1)[sc * BD4 + col];
  float4 S2 = ((const float4*)sup2)[sc * BD4 + col];
  float csum = supc[sc * B_DIM + b];
  for (int j = sc * G; j < chunk; ++j) {
    float4 a = ((const float4*)s1p)[j * BD4 + col];
    float4 d = ((const float4*)s2p)[j * BD4 + col];
    S1 = f4add(S1, a);
    S2 = f4add(S2, d);
    csum += cnt[j * B_DIM + b];  // uniform -> broadcast load
  }
  float c = C0 + csum;

  float4 pm4 = ((const float4*)pm)[tid];
  float4 lv4 = ((const float4*)plv)[tid];
  float4 g4  = ((const float4*)w)[tid];
  float4 be4 = ((const float4*)bias)[tid];
  g4.x += 1.f; g4.y += 1.f; g4.z += 1.f; g4.w += 1.f;
  float M0x = C0 * pm4.x, M0y = C0 * pm4.y, M0z = C0 * pm4.z, M0w = C0 * pm4.w;
  float V2x = C0 * (__expf(lv4.x) + pm4.x * pm4.x);
  float V2y = C0 * (__expf(lv4.y) + pm4.y * pm4.y);
  float V2z = C0 * (__expf(lv4.z) + pm4.z * pm4.z);
  float V2w = C0 * (__expf(lv4.w) + pm4.w * pm4.w);

  unsigned long long mw[NWF];
  const unsigned long long* m8 =
      (const unsigned long long*)(mask + b * T_DIM + t0);
#pragma unroll
  for (int j = 0; j < NWF; ++j) mw[j] = m8[j];

  const float4* xp = (const float4*)x;
  float4* op = (float4*)out;

#pragma unroll 4
  for (int i = 0; i < CTF; ++i) {
    float valid = ((mw[i >> 3] >> ((i & 7) * 8)) & 0xffULL) ? 0.f : 1.f;
    const int xi = (t0 + i) * BD4 + col;
    float4 v = xp[xi];  // L3-resident from pass1's streaming read
    c += valid;
    float rc = __builtin_amdgcn_rcpf(c);
    float4 y;
    {
      S1.x += valid * v.x; S2.x += valid * v.x * v.x;
      float M = M0x + S1.x;
      float mean = M * rc;
      float var = (V2x + S2.x - M * M * rc) * rc;
      y.x = (v.x - mean) * __builtin_amdgcn_rsqf(var + EPS) * g4.x + be4.x;
    }
    {
      S1.y += valid * v.y; S2.y += valid * v.y * v.y;
      float M = M0y + S1.y;
      float mean = M * rc;
      float var = (V2y + S2.y - M * M * rc) * rc;
      y.y = (v.y - mean) * __builtin_amdgcn_rsqf(var + EPS) * g4.y + be4.y;
    }
    {
      S1.z += valid * v.z; S2.z += valid * v.z * v.z;
      float M = M0z + S1.z;
      float mean = M * rc;
      float var = (V2z + S2.z - M * M * rc) * rc;
      y.z = (v.z - mean) * __builtin_amdgcn_rsqf(var + EPS) * g4.z + be4.z;
    }
    {
      S1.w += valid * v.w; S2.w += valid * v.w * v.w;
      float M = M0w + S1.w;
      float mean = M * rc;
      float var = (V2w + S2.w - M * M * rc) * rc;
      y.w = (v.w - mean) * __builtin_amdgcn_rsqf(var + EPS) * g4.w + be4.w;
    }
    // y never re-read: nontemporal store (no write-allocate; keeps x in L3).
    ntstore4(y, &op[xi]);
  }
}

// ---------------- launch ----------------
extern "C" void kernel_launch(void* const* d_in, const int* in_sizes, int n_in,
                              void* d_out, int out_size, void* d_ws,
                              size_t ws_size, hipStream_t stream) {
  const float* x    = (const float*)d_in[0];
  const float* pm   = (const float*)d_in[1];
  const float* plv  = (const float*)d_in[2];
  const float* w    = (const float*)d_in[3];
  const float* bias = (const float*)d_in[4];
  const unsigned char* mask = (const unsigned char*)d_in[5];
  float* out = (float*)d_out;
  float* ws  = (float*)d_ws;

  // ws layout: s1p, s2p [NCF*BD] | cnt [NCF*B] | sup1, sup2 [NSC*BD] |
  //            supc [NSC*B]   (~17.8 MB total; ws is 512 MiB)
  float* s1p  = ws;
  float* s2p  = s1p + (size_t)NCF * BD;
  float* cnt  = s2p + (size_t)NCF * BD;
  float* sup1 = cnt + (size_t)NCF * B_DIM;
  float* sup2 = sup1 + (size_t)NSC * BD;
  float* supc = sup2 + (size_t)NSC * BD;

  dim3 grid(NCF, B_DIM);
  ts_pass1<<<grid, 128, 0, stream>>>(x, mask, s1p, s2p, cnt);
  const int scan_waves = 2 * BD4 + B_DIM;        // 2056
  const int scan_blocks = (scan_waves + 3) / 4;  // 514 blocks of 4 waves
  ts_pass2sup<<<scan_blocks, 256, 0, stream>>>(s1p, s2p, cnt, sup1, sup2,
                                               supc);
  ts_pass3<<<grid, 128, 0, stream>>>(x, mask, pm, plv, w, bias, s1p, s2p, cnt,
                                     sup1, sup2, supc, out);
}

// Round 8
// 276.096 us; speedup vs baseline: 6.7183x; 1.0401x over previous
//
#include <hip/hip_runtime.h>
#include <math.h>

// TimestepNorm forward, prefix-sum reformulation:
//   c_t   = C0 + #valid<=t
//   M_t   = C0*pm + sum(valid*x)             -> mean = M/c
//   var_t = (V2 + sum(valid*x^2) - M_t^2/c_t)/c_t,  V2 = C0*(exp(plv)+pm^2)
//
// v9 = exact revert to v6 (verified 277.1 us), the session's best.
// 3-pass chunked scan, NC=512 (CT=16, 4096 blocks x 128 thr, 32 waves/CU):
//   pass1: per-chunk partials (valid*x, valid*x^2, count)
//   pass2: wave-parallel in-place exclusive scan over chunks (1 wave/column)
//   pass3: O(1)-prefix replay + normalize epilogue, nontemporal y-stores
// Tested and rejected this session:
//   v3  decoupled lookback fusion     914 us  (serial flag-walk chain)
//   v5  nt x-loads in pass3           neutral (L3 behavior unchanged)
//   v7  cooperative grid.sync fusion 1725 us  (multi-XCD barrier cost at
//                                              full 98.8% residency)
//   v8  superchunk pass2 + prologue   287 us  (+180 MB L3 prologue reads)
// Fixed harness cost ~174 us (512 MiB ws poison fills) is untouchable.

#define T_DIM 8192
#define B_DIM 8
#define D_DIM 512
#define BD    (B_DIM * D_DIM)   // 4096 floats per time row
#define BD4   (BD / 4)          // 1024 float4 per time row
#define D4    (D_DIM / 4)       // 128 float4 per (t,b)
#define C0    2.0f              // PRIOR_COUNT
#define EPS   1e-5f

typedef float nt_f4 __attribute__((ext_vector_type(4)));

__device__ __forceinline__ float4 f4add(float4 a, float4 b) {
  return make_float4(a.x + b.x, a.y + b.y, a.z + b.z, a.w + b.w);
}
__device__ __forceinline__ float4 f4sub(float4 a, float4 b) {
  return make_float4(a.x - b.x, a.y - b.y, a.z - b.z, a.w - b.w);
}

__device__ __forceinline__ void ntstore4(float4 v, float4* p) {
  nt_f4 t = {v.x, v.y, v.z, v.w};
  __builtin_nontemporal_store(t, (nt_f4*)p);
}

// ---------------- pass1: per-chunk partial sums ----------------
template <int NC>
__global__ __launch_bounds__(128) void ts_pass1(
    const float* __restrict__ x, const unsigned char* __restrict__ mask,
    float* __restrict__ s1p, float* __restrict__ s2p, float* __restrict__ cnt) {
  constexpr int CT = T_DIM / NC;
  constexpr int NW = CT / 8;
  const int chunk = blockIdx.x;
  const int b     = blockIdx.y;
  const int tid   = threadIdx.x;
  const int t0    = chunk * CT;
  const float4* xp = (const float4*)x;

  unsigned long long mw[NW];
  const unsigned long long* m8 =
      (const unsigned long long*)(mask + b * T_DIM + t0);
#pragma unroll
  for (int j = 0; j < NW; ++j) mw[j] = m8[j];

  float4 s1 = make_float4(0.f, 0.f, 0.f, 0.f);
  float4 s2 = make_float4(0.f, 0.f, 0.f, 0.f);
  float c = 0.f;
#pragma unroll 8
  for (int i = 0; i < CT; ++i) {
    float valid = ((mw[i >> 3] >> ((i & 7) * 8)) & 0xffULL) ? 0.f : 1.f;
    float4 v = xp[(t0 + i) * BD4 + b * D4 + tid];
    c += valid;
    s1.x += valid * v.x; s2.x += valid * v.x * v.x;
    s1.y += valid * v.y; s2.y += valid * v.y * v.y;
    s1.z += valid * v.z; s2.z += valid * v.z * v.z;
    s1.w += valid * v.w; s2.w += valid * v.w * v.w;
  }
  const int pidx = chunk * BD4 + b * D4 + tid;
  ((float4*)s1p)[pidx] = s1;
  ((float4*)s2p)[pidx] = s2;
  if (tid == 0) cnt[chunk * B_DIM + b] = c;
}

// ---------------- pass2: wave-parallel exclusive scan over chunks ----------
// One wave per column. s1p/s2p: 2*BD4 float4-columns of length NC (stride BD4
// float4). cnt: B_DIM scalar columns of length NC (stride B_DIM). In-place:
// each column is owned by exactly one wave.
template <int NC>
__global__ __launch_bounds__(256) void ts_pass2(
    float* __restrict__ s1p, float* __restrict__ s2p, float* __restrict__ cnt) {
  constexpr int KPL = NC / 64;  // chunks per lane
  const int wid  = (blockIdx.x * 256 + threadIdx.x) >> 6;
  const int lane = threadIdx.x & 63;

  if (wid < 2 * BD4) {
    float4* base = (float4*)(wid < BD4 ? s1p : s2p);
    const int col = wid & (BD4 - 1);
    float4 vals[KPL];
#pragma unroll
    for (int j = 0; j < KPL; ++j)
      vals[j] = base[(lane * KPL + j) * BD4 + col];
#pragma unroll
    for (int j = 1; j < KPL; ++j) vals[j] = f4add(vals[j], vals[j - 1]);
    float4 tot = vals[KPL - 1];
    float4 inc = tot;
#pragma unroll
    for (int off = 1; off < 64; off <<= 1) {
      float4 o;
      o.x = __shfl_up(inc.x, off);
      o.y = __shfl_up(inc.y, off);
      o.z = __shfl_up(inc.z, off);
      o.w = __shfl_up(inc.w, off);
      if (lane >= off) inc = f4add(inc, o);
    }
    float4 excl = f4sub(inc, tot);  // exclusive prefix of this lane's segment
#pragma unroll
    for (int j = KPL - 1; j >= 1; --j)
      base[(lane * KPL + j) * BD4 + col] = f4add(excl, vals[j - 1]);
    base[(lane * KPL) * BD4 + col] = excl;
  } else if (wid < 2 * BD4 + B_DIM) {
    const int b = wid - 2 * BD4;
    float vals[KPL];
#pragma unroll
    for (int j = 0; j < KPL; ++j) vals[j] = cnt[(lane * KPL + j) * B_DIM + b];
#pragma unroll
    for (int j = 1; j < KPL; ++j) vals[j] += vals[j - 1];
    float tot = vals[KPL - 1];
    float inc = tot;
#pragma unroll
    for (int off = 1; off < 64; off <<= 1) {
      float o = __shfl_up(inc, off);
      if (lane >= off) inc += o;
    }
    float excl = inc - tot;
#pragma unroll
    for (int j = KPL - 1; j >= 1; --j)
      cnt[(lane * KPL + j) * B_DIM + b] = excl + vals[j - 1];
    cnt[lane * KPL * B_DIM + b] = excl;
  }
}

// ---------------- pass3: replay chunk with y epilogue ----------------
template <int NC>
__global__ __launch_bounds__(128) void ts_pass3(
    const float* __restrict__ x, const unsigned char* __restrict__ mask,
    const float* __restrict__ pm, const float* __restrict__ plv,
    const float* __restrict__ w, const float* __restrict__ bias,
    const float* __restrict__ e1, const float* __restrict__ e2,
    const float* __restrict__ ecnt, float* __restrict__ out) {
  constexpr int CT = T_DIM / NC;
  constexpr int NW = CT / 8;
  const int chunk = blockIdx.x;
  const int b     = blockIdx.y;
  const int tid   = threadIdx.x;
  const int t0    = chunk * CT;
  const int col   = b * D4 + tid;

  // Exclusive chunk prefix: O(1) loads (pass2 already scanned).
  float4 S1 = ((const float4*)e1)[chunk * BD4 + col];
  float4 S2 = ((const float4*)e2)[chunk * BD4 + col];
  float c = C0 + ecnt[chunk * B_DIM + b];

  float4 pm4 = ((const float4*)pm)[tid];
  float4 lv4 = ((const float4*)plv)[tid];
  float4 g4  = ((const float4*)w)[tid];
  float4 be4 = ((const float4*)bias)[tid];
  g4.x += 1.f; g4.y += 1.f; g4.z += 1.f; g4.w += 1.f;
  float M0x = C0 * pm4.x, M0y = C0 * pm4.y, M0z = C0 * pm4.z, M0w = C0 * pm4.w;
  float V2x = C0 * (__expf(lv4.x) + pm4.x * pm4.x);
  float V2y = C0 * (__expf(lv4.y) + pm4.y * pm4.y);
  float V2z = C0 * (__expf(lv4.z) + pm4.z * pm4.z);
  float V2w = C0 * (__expf(lv4.w) + pm4.w * pm4.w);

  unsigned long long mw[NW];
  const unsigned long long* m8 =
      (const unsigned long long*)(mask + b * T_DIM + t0);
#pragma unroll
  for (int j = 0; j < NW; ++j) mw[j] = m8[j];

  const float4* xp = (const float4*)x;
  float4* op = (float4*)out;

#pragma unroll 4
  for (int i = 0; i < CT; ++i) {
    float valid = ((mw[i >> 3] >> ((i & 7) * 8)) & 0xffULL) ? 0.f : 1.f;
    const int xi = (t0 + i) * BD4 + col;
    float4 v = xp[xi];  // L3-resident from pass1's streaming read
    c += valid;
    float rc = __builtin_amdgcn_rcpf(c);
    float4 y;
    {
      S1.x += valid * v.x; S2.x += valid * v.x * v.x;
      float M = M0x + S1.x;
      float mean = M * rc;
      float var = (V2x + S2.x - M * M * rc) * rc;
      y.x = (v.x - mean) * __builtin_amdgcn_rsqf(var + EPS) * g4.x + be4.x;
    }
    {
      S1.y += valid * v.y; S2.y += valid * v.y * v.y;
      float M = M0y + S1.y;
      float mean = M * rc;
      float var = (V2y + S2.y - M * M * rc) * rc;
      y.y = (v.y - mean) * __builtin_amdgcn_rsqf(var + EPS) * g4.y + be4.y;
    }
    {
      S1.z += valid * v.z; S2.z += valid * v.z * v.z;
      float M = M0z + S1.z;
      float mean = M * rc;
      float var = (V2z + S2.z - M * M * rc) * rc;
      y.z = (v.z - mean) * __builtin_amdgcn_rsqf(var + EPS) * g4.z + be4.z;
    }
    {
      S1.w += valid * v.w; S2.w += valid * v.w * v.w;
      float M = M0w + S1.w;
      float mean = M * rc;
      float var = (V2w + S2.w - M * M * rc) * rc;
      y.w = (v.w - mean) * __builtin_amdgcn_rsqf(var + EPS) * g4.w + be4.w;
    }
    // y never re-read: nontemporal store (no write-allocate; keeps x in L3).
    ntstore4(y, &op[xi]);
  }
}

// ---------------- launch ----------------
template <int NC>
static void run_3pass(const float* x, const unsigned char* mask,
                      const float* pm, const float* plv, const float* w,
                      const float* bias, float* out, float* ws,
                      hipStream_t stream) {
  float* s1p = ws;
  float* s2p = s1p + (size_t)NC * BD;
  float* cnt = s2p + (size_t)NC * BD;
  dim3 grid(NC, B_DIM);
  ts_pass1<NC><<<grid, 128, 0, stream>>>(x, mask, s1p, s2p, cnt);
  const int scan_waves = 2 * BD4 + B_DIM;        // 2056
  const int scan_blocks = (scan_waves + 3) / 4;  // 514 blocks of 4 waves
  ts_pass2<NC><<<scan_blocks, 256, 0, stream>>>(s1p, s2p, cnt);
  ts_pass3<NC><<<grid, 128, 0, stream>>>(x, mask, pm, plv, w, bias, s1p, s2p,
                                         cnt, out);
}

extern "C" void kernel_launch(void* const* d_in, const int* in_sizes, int n_in,
                              void* d_out, int out_size, void* d_ws,
                              size_t ws_size, hipStream_t stream) {
  const float* x    = (const float*)d_in[0];
  const float* pm   = (const float*)d_in[1];
  const float* plv  = (const float*)d_in[2];
  const float* w    = (const float*)d_in[3];
  const float* bias = (const float*)d_in[4];
  const unsigned char* mask = (const unsigned char*)d_in[5];
  float* out = (float*)d_out;
  float* ws  = (float*)d_ws;

  const size_t need512 = ((size_t)2 * 512 * BD + 512 * B_DIM) * sizeof(float);
  const size_t need256 = ((size_t)2 * 256 * BD + 256 * B_DIM) * sizeof(float);
  if (ws_size >= need512) {
    run_3pass<512>(x, mask, pm, plv, w, bias, out, ws, stream);
  } else if (ws_size >= need256) {
    run_3pass<256>(x, mask, pm, plv, w, bias, out, ws, stream);
  } else {
    run_3pass<128>(x, mask, pm, plv, w, bias, out, ws, stream);
  }
}